// Round 27
// baseline (28.901 us; speedup 1.0000x reference)
//
#include <hip/hip_runtime.h>
#include <hip/hip_fp16.h>

typedef __attribute__((ext_vector_type(4))) float f32x4;
typedef __attribute__((ext_vector_type(8))) int i32x8;

#define NROWS 8192
#define DCOLS 256
#define MARGIN 0.5f
#define NT 64          // 8192/128 tiles per dim
#define NBLOCKS 512    // exact: rows bi<=10 runs-of-5 (134) + bi>=11 runs-of-4 (378)

// --- Kernel 1: L2-normalize rows fp32 -> fp8 e5m2 (= truncated fp16), row-major.
__global__ __launch_bounds__(256) void norm_kernel(const float* __restrict__ x,
                                                   unsigned char* __restrict__ e) {
    const int t = threadIdx.x;
    const int l = t & 63;
    const int c = l & 31;
    const int row = blockIdx.x * 8 + (t >> 6) * 2 + (l >> 5);

    const float4 v0 = *reinterpret_cast<const float4*>(&x[row * DCOLS + c * 8]);
    const float4 v1 = *reinterpret_cast<const float4*>(&x[row * DCOLS + c * 8 + 4]);
    float ss = v0.x * v0.x + v0.y * v0.y + v0.z * v0.z + v0.w * v0.w
             + v1.x * v1.x + v1.y * v1.y + v1.z * v1.z + v1.w * v1.w;
#pragma unroll
    for (int off = 16; off >= 1; off >>= 1) ss += __shfl_xor(ss, off, 32);
    const float inv = 1.0f / fmaxf(sqrtf(ss), 1e-12f);

    const float f[8] = {v0.x, v0.y, v0.z, v0.w, v1.x, v1.y, v1.z, v1.w};
    unsigned int lo = 0, hi = 0;
#pragma unroll
    for (int i = 0; i < 4; ++i) {
        const unsigned short hb = __half_as_ushort(__float2half(f[i] * inv));
        lo |= (unsigned int)(hb >> 8) << (8 * i);           // e5m2 = fp16 top byte
    }
#pragma unroll
    for (int i = 0; i < 4; ++i) {
        const unsigned short hb = __half_as_ushort(__float2half(f[4 + i] * inv));
        hi |= (unsigned int)(hb >> 8) << (8 * i);
    }
    uint2 o; o.x = lo; o.y = hi;
    *reinterpret_cast<uint2*>(e + (size_t)row * DCOLS + c * 8) = o;
}

// --- Kernel 2: R27 = R26 champion with an exact-512 balanced partition:
// rows bi<=10 (L>=54 tiles) use runs-of-5, rows bi>=11 runs-of-4 ->
// 134 + 378 = 512 blocks = exactly 2 blocks/CU on 256 CUs (no idle CUs,
// no serial generation). Pipeline byte-identical to the champion: 256 thr =
// 4 free waves, tile 128x128, wave owns cols wn*32 -> acc[8][2] of
// mfma_scale_f32_16x16x128 (bf8/bf8, scale=1.0, verified in-context R18).
// A hoisted to af[2][8] regs via 16KB LDS bounce (2 rounds); B wave-private
// 4KB ring-3, own-vmcnt counted gating (vmcnt(4)), no in-loop barriers.
// LDS 64KB -> 2 blocks/CU.
__global__ __launch_bounds__(256, 2) void tile_kernel(const unsigned char* __restrict__ e,
                                                      float* __restrict__ part) {
    // exact XCD swizzle (512 = 8*64), then row/run decode (mixed 5/4 runs)
    const int orig = blockIdx.x;
    int bb = (orig & 7) * 64 + (orig >> 3);
    int bi = 0, r;
    for (;;) {
        const int RS = (bi <= 10) ? 5 : 4;
        r = ((NT - bi) + RS - 1) / RS;
        if (bb < r) break;
        bb -= r; ++bi;
    }
    const int RS = (bi <= 10) ? 5 : 4;
    const int j0 = bi + bb * RS;
    const int nj = min(RS, NT - j0);
    const int NS = nj * 2;                    // K128-steps (<=10)

    __shared__ char lds[65536];               // [0,16K): A bounce ; [16K,64K): Bw
    char* As = lds;                           // 16KB: [hk][row128][32B]
    char* Bw = lds + 16384;                   // 4 waves x 3 slots x 4KB
    float* red = (float*)lds;                 // reuse dead A region at the end

    const int t = threadIdx.x;
    const int l = t & 63;
    const int w = t >> 6;       // wave id = N-slice: cols wn*32
    const int wn = w;
    const int lr = l & 15;
    const int hk = l >> 4;
    const unsigned char* eA = e + (size_t)bi * 128 * DCOLS;
    const unsigned char* eB = e + (size_t)j0 * 128 * DCOLS + wn * 32 * DCOLS;
    char* myB = Bw + w * 12288;

    // stage one B K128-panel (stream s: tile j0+(s>>1), kblock s&1) into a slot.
    auto stageB = [&](int stream, int slot) {
#pragma unroll
        for (int i = 0; i < 4; ++i) {
            const int u = i * 64 + l;
            const int shk = (u >> 6) & 3, srow = (u >> 1) & 31, sc = u & 1;
            __builtin_amdgcn_global_load_lds(
                (const __attribute__((address_space(1))) void*)(eB
                    + (size_t)(stream >> 1) * 128 * DCOLS
                    + srow * DCOLS + (stream & 1) * 128 + shk * 32 + sc * 16),
                (__attribute__((address_space(3))) void*)(myB + slot * 4096 + u * 16),
                16, 0, 0);
        }
    };

    // --- prologue ---
    // A round 0 (kblock 0): 4 loads/thread.
#pragma unroll
    for (int i = 0; i < 4; ++i) {
        const int u = i * 256 + t;
        const int shk = (u >> 8) & 3, srow = (u >> 1) & 127, sc = u & 1;
        __builtin_amdgcn_global_load_lds(
            (const __attribute__((address_space(1))) void*)(eA + srow * DCOLS + shk * 32 + sc * 16),
            (__attribute__((address_space(3))) void*)(As + u * 16), 16, 0, 0);
    }
    stageB(0, 0);
    stageB(1, 1);
    asm volatile("s_waitcnt vmcnt(8)" ::: "memory");   // A0 landed; 8 B in flight
    __builtin_amdgcn_s_barrier();
    __builtin_amdgcn_sched_barrier(0);

    i32x8 af[2][8];
#pragma unroll
    for (int m = 0; m < 8; ++m)
        af[0][m] = *reinterpret_cast<const i32x8*>(As + hk * 4096 + (m * 16 + lr) * 32);
    __builtin_amdgcn_s_barrier();             // all waves done reading A0
    __builtin_amdgcn_sched_barrier(0);
    // A round 1 (kblock 1) into the same 16KB
#pragma unroll
    for (int i = 0; i < 4; ++i) {
        const int u = i * 256 + t;
        const int shk = (u >> 8) & 3, srow = (u >> 1) & 127, sc = u & 1;
        __builtin_amdgcn_global_load_lds(
            (const __attribute__((address_space(1))) void*)(eA + srow * DCOLS + 128 + shk * 32 + sc * 16),
            (__attribute__((address_space(3))) void*)(As + u * 16), 16, 0, 0);
    }
    asm volatile("s_waitcnt vmcnt(0)" ::: "memory");   // drain (prologue-only)
    __builtin_amdgcn_s_barrier();
    __builtin_amdgcn_sched_barrier(0);
#pragma unroll
    for (int m = 0; m < 8; ++m)
        af[1][m] = *reinterpret_cast<const i32x8*>(As + hk * 4096 + (m * 16 + lr) * 32);
    // As now dead (red[] reuses it after the loop). B streams 0,1 landed.

    f32x4 acc[8][2];
#pragma unroll
    for (int m = 0; m < 8; ++m)
#pragma unroll
        for (int n = 0; n < 2; ++n)
            acc[m][n] = (f32x4){0.f, 0.f, 0.f, 0.f};

    float local = 0.0f;
    for (int jx = 0; jx < nj; ++jx) {
        const int jt = j0 + jx;
#pragma unroll
        for (int kb = 0; kb < 2; ++kb) {
            const int s = jx * 2 + kb;
            // own oldest B stage has landed (counted; trivially true for s<2)
            asm volatile("s_waitcnt vmcnt(4)" ::: "memory");
            // stage stream s+2 into slot (s+2)%3 (wrap: identical bytes, benign)
            {
                int s2 = s + 2; if (s2 >= NS) s2 -= NS;
                int slot = s + 2; while (slot >= 3) slot -= 3;
                stageB(s2, slot);
            }
            int slotc = s; while (slotc >= 3) slotc -= 3;
            i32x8 bf[2];
#pragma unroll
            for (int n = 0; n < 2; ++n)
                bf[n] = *reinterpret_cast<const i32x8*>(
                    myB + slotc * 4096 + hk * 1024 + (n * 16 + lr) * 32);
            __builtin_amdgcn_s_setprio(1);
#pragma unroll
            for (int m = 0; m < 8; ++m)
#pragma unroll
                for (int n = 0; n < 2; ++n)
                    acc[m][n] = __builtin_amdgcn_mfma_scale_f32_16x16x128_f8f6f4(
                        af[kb][m], bf[n], acc[m][n],
                        1, 1,                     // cbsz=BF8(e5m2), blgp=BF8
                        0, 0x7F7F7F7F,            // scale A = 1.0
                        0, 0x7F7F7F7F);           // scale B = 1.0
            __builtin_amdgcn_s_setprio(0);
        }
        // --- tile jt complete: fused masked-relu reduce, reset acc ---
        // C/D layout (m89-verified; shape-determined for f8f6f4): col=lane&15,
        // row=(lane>>4)*4+reg.
        const int gi0 = bi * 128;
        const int gj0 = jt * 128 + wn * 32;
        if (jt == bi) {
#pragma unroll
            for (int m = 0; m < 8; ++m)
#pragma unroll
                for (int n = 0; n < 2; ++n) {
#pragma unroll
                    for (int r2 = 0; r2 < 4; ++r2) {
                        const int gi = gi0 + m * 16 + hk * 4 + r2;
                        const int gj = gj0 + n * 16 + lr;
                        local += (gi < gj) ? fmaxf(acc[m][n][r2] - MARGIN, 0.0f) : 0.0f;
                    }
                    acc[m][n] = (f32x4){0.f, 0.f, 0.f, 0.f};
                }
        } else {   // jt > bi: all pairs strictly upper-triangular
#pragma unroll
            for (int m = 0; m < 8; ++m)
#pragma unroll
                for (int n = 0; n < 2; ++n) {
#pragma unroll
                    for (int r2 = 0; r2 < 4; ++r2)
                        local += fmaxf(acc[m][n][r2] - MARGIN, 0.0f);
                    acc[m][n] = (f32x4){0.f, 0.f, 0.f, 0.f};
                }
        }
    }

    // --- block reduction -> one partial per block, no atomics ---
#pragma unroll
    for (int off = 32; off >= 1; off >>= 1) local += __shfl_down(local, off);
    __syncthreads();                          // all loop-LDS traffic done
    if (l == 0) red[w] = local;
    __syncthreads();
    if (t == 0) part[orig] = red[0] + red[1] + red[2] + red[3];
}

// --- Kernel 3: reduce NBLOCKS=512 partials, finalize ---
__global__ __launch_bounds__(256) void fin_kernel(const float* __restrict__ part,
                                                  float* __restrict__ out) {
    __shared__ float red[4];
    const int t = threadIdx.x;
    float v = part[t] + part[t + 256];
#pragma unroll
    for (int off = 32; off >= 1; off >>= 1) v += __shfl_down(v, off);
    if ((t & 63) == 0) red[t >> 6] = v;
    __syncthreads();
    if (t == 0) out[0] = (red[0] + red[1] + red[2] + red[3]) / 33550336.0f;
}

extern "C" void kernel_launch(void* const* d_in, const int* in_sizes, int n_in,
                              void* d_out, int out_size, void* d_ws, size_t ws_size,
                              hipStream_t stream) {
    const float* x = (const float*)d_in[0];
    float* out = (float*)d_out;
    unsigned char* e = (unsigned char*)d_ws;                        // 2 MB fp8
    float* part = (float*)((char*)d_ws + (size_t)NROWS * DCOLS);    // 512 floats

    norm_kernel<<<NROWS / 8, 256, 0, stream>>>(x, e);
    tile_kernel<<<NBLOCKS, 256, 0, stream>>>(e, part);
    fin_kernel<<<1, 256, 0, stream>>>(part, out);
}

// Round 28
// 28.182 us; speedup vs baseline: 1.0255x; 1.0255x over previous
//
#include <hip/hip_runtime.h>
#include <hip/hip_fp16.h>

typedef __attribute__((ext_vector_type(4))) float f32x4;
typedef __attribute__((ext_vector_type(8))) int i32x8;

#define NROWS 8192
#define DCOLS 256
#define MARGIN 0.5f
#define NT 64          // 8192/128 tiles per dim
#define NBLOCKS 442    // sum over rows bi of ceil((64-bi)/5), runs of <=5

// --- Kernel 1: L2-normalize rows fp32 -> fp8 e5m2 (= truncated fp16), row-major.
__global__ __launch_bounds__(256) void norm_kernel(const float* __restrict__ x,
                                                   unsigned char* __restrict__ e) {
    const int t = threadIdx.x;
    const int l = t & 63;
    const int c = l & 31;
    const int row = blockIdx.x * 8 + (t >> 6) * 2 + (l >> 5);

    const float4 v0 = *reinterpret_cast<const float4*>(&x[row * DCOLS + c * 8]);
    const float4 v1 = *reinterpret_cast<const float4*>(&x[row * DCOLS + c * 8 + 4]);
    float ss = v0.x * v0.x + v0.y * v0.y + v0.z * v0.z + v0.w * v0.w
             + v1.x * v1.x + v1.y * v1.y + v1.z * v1.z + v1.w * v1.w;
#pragma unroll
    for (int off = 16; off >= 1; off >>= 1) ss += __shfl_xor(ss, off, 32);
    const float inv = 1.0f / fmaxf(sqrtf(ss), 1e-12f);

    const float f[8] = {v0.x, v0.y, v0.z, v0.w, v1.x, v1.y, v1.z, v1.w};
    unsigned int lo = 0, hi = 0;
#pragma unroll
    for (int i = 0; i < 4; ++i) {
        const unsigned short hb = __half_as_ushort(__float2half(f[i] * inv));
        lo |= (unsigned int)(hb >> 8) << (8 * i);           // e5m2 = fp16 top byte
    }
#pragma unroll
    for (int i = 0; i < 4; ++i) {
        const unsigned short hb = __half_as_ushort(__float2half(f[4 + i] * inv));
        hi |= (unsigned int)(hb >> 8) << (8 * i);
    }
    uint2 o; o.x = lo; o.y = hi;
    *reinterpret_cast<uint2*>(e + (size_t)row * DCOLS + c * 8) = o;
}

// --- Kernel 2 (SESSION CHAMPION, R26 = 27.8us): MX-fp8 K=128 MFMA +
// A-in-registers + barrier-free wave-private B pipeline + single-generation
// grid (runs of <=5 -> 442 blocks <= 512 co-residency slots, no serial tail).
// Block = (bi, run of <=5 j-tiles), 256 thr = 4 free waves. Tile 128x128;
// wave owns cols wn*32: acc[8][2] of mfma_scale_f32_16x16x128 (bf8/bf8,
// scale=1.0, verified in-context R18). A panel hoisted to af[2][8] regs via
// 16KB LDS bounce (2 rounds); B wave-private 4KB ring-3, own-vmcnt counted
// gating (vmcnt(4)), no in-loop barriers. LDS 64KB -> 2 blocks/CU.
__global__ __launch_bounds__(256, 2) void tile_kernel(const unsigned char* __restrict__ e,
                                                      float* __restrict__ part) {
    // bijective XCD remap for 442 = 8*55 + 2 (m204 q/r formula, ERRATA #11)
    const int orig = blockIdx.x;
    const int xcd = orig & 7, idx = orig >> 3;
    int bb = (xcd < 2 ? xcd * 56 : 2 * 56 + (xcd - 2) * 55) + idx;
    int bi = 0, r;
    while (bb >= (r = ((NT - bi) + 4) / 5)) { bb -= r; ++bi; }
    const int j0 = bi + bb * 5;
    const int nj = min(5, NT - j0);
    const int NS = nj * 2;                    // K128-steps (<=10)

    __shared__ char lds[65536];               // [0,16K): A bounce ; [16K,64K): Bw
    char* As = lds;                           // 16KB: [hk][row128][32B]
    char* Bw = lds + 16384;                   // 4 waves x 3 slots x 4KB
    float* red = (float*)lds;                 // reuse dead A region at the end

    const int t = threadIdx.x;
    const int l = t & 63;
    const int w = t >> 6;       // wave id = N-slice: cols wn*32
    const int wn = w;
    const int lr = l & 15;
    const int hk = l >> 4;
    const unsigned char* eA = e + (size_t)bi * 128 * DCOLS;
    const unsigned char* eB = e + (size_t)j0 * 128 * DCOLS + wn * 32 * DCOLS;
    char* myB = Bw + w * 12288;

    // stage one B K128-panel (stream s: tile j0+(s>>1), kblock s&1) into a slot.
    auto stageB = [&](int stream, int slot) {
#pragma unroll
        for (int i = 0; i < 4; ++i) {
            const int u = i * 64 + l;
            const int shk = (u >> 6) & 3, srow = (u >> 1) & 31, sc = u & 1;
            __builtin_amdgcn_global_load_lds(
                (const __attribute__((address_space(1))) void*)(eB
                    + (size_t)(stream >> 1) * 128 * DCOLS
                    + srow * DCOLS + (stream & 1) * 128 + shk * 32 + sc * 16),
                (__attribute__((address_space(3))) void*)(myB + slot * 4096 + u * 16),
                16, 0, 0);
        }
    };

    // --- prologue ---
    // A round 0 (kblock 0): 4 loads/thread.
#pragma unroll
    for (int i = 0; i < 4; ++i) {
        const int u = i * 256 + t;
        const int shk = (u >> 8) & 3, srow = (u >> 1) & 127, sc = u & 1;
        __builtin_amdgcn_global_load_lds(
            (const __attribute__((address_space(1))) void*)(eA + srow * DCOLS + shk * 32 + sc * 16),
            (__attribute__((address_space(3))) void*)(As + u * 16), 16, 0, 0);
    }
    stageB(0, 0);
    stageB(1, 1);
    asm volatile("s_waitcnt vmcnt(8)" ::: "memory");   // A0 landed; 8 B in flight
    __builtin_amdgcn_s_barrier();
    __builtin_amdgcn_sched_barrier(0);

    i32x8 af[2][8];
#pragma unroll
    for (int m = 0; m < 8; ++m)
        af[0][m] = *reinterpret_cast<const i32x8*>(As + hk * 4096 + (m * 16 + lr) * 32);
    __builtin_amdgcn_s_barrier();             // all waves done reading A0
    __builtin_amdgcn_sched_barrier(0);
    // A round 1 (kblock 1) into the same 16KB
#pragma unroll
    for (int i = 0; i < 4; ++i) {
        const int u = i * 256 + t;
        const int shk = (u >> 8) & 3, srow = (u >> 1) & 127, sc = u & 1;
        __builtin_amdgcn_global_load_lds(
            (const __attribute__((address_space(1))) void*)(eA + srow * DCOLS + 128 + shk * 32 + sc * 16),
            (__attribute__((address_space(3))) void*)(As + u * 16), 16, 0, 0);
    }
    asm volatile("s_waitcnt vmcnt(0)" ::: "memory");   // drain (prologue-only)
    __builtin_amdgcn_s_barrier();
    __builtin_amdgcn_sched_barrier(0);
#pragma unroll
    for (int m = 0; m < 8; ++m)
        af[1][m] = *reinterpret_cast<const i32x8*>(As + hk * 4096 + (m * 16 + lr) * 32);
    // As now dead (red[] reuses it after the loop). B streams 0,1 landed.

    f32x4 acc[8][2];
#pragma unroll
    for (int m = 0; m < 8; ++m)
#pragma unroll
        for (int n = 0; n < 2; ++n)
            acc[m][n] = (f32x4){0.f, 0.f, 0.f, 0.f};

    float local = 0.0f;
    for (int jx = 0; jx < nj; ++jx) {
        const int jt = j0 + jx;
#pragma unroll
        for (int kb = 0; kb < 2; ++kb) {
            const int s = jx * 2 + kb;
            // own oldest B stage has landed (counted; trivially true for s<2)
            asm volatile("s_waitcnt vmcnt(4)" ::: "memory");
            // stage stream s+2 into slot (s+2)%3 (wrap: identical bytes, benign)
            {
                int s2 = s + 2; if (s2 >= NS) s2 -= NS;
                int slot = s + 2; while (slot >= 3) slot -= 3;
                stageB(s2, slot);
            }
            int slotc = s; while (slotc >= 3) slotc -= 3;
            i32x8 bf[2];
#pragma unroll
            for (int n = 0; n < 2; ++n)
                bf[n] = *reinterpret_cast<const i32x8*>(
                    myB + slotc * 4096 + hk * 1024 + (n * 16 + lr) * 32);
            __builtin_amdgcn_s_setprio(1);
#pragma unroll
            for (int m = 0; m < 8; ++m)
#pragma unroll
                for (int n = 0; n < 2; ++n)
                    acc[m][n] = __builtin_amdgcn_mfma_scale_f32_16x16x128_f8f6f4(
                        af[kb][m], bf[n], acc[m][n],
                        1, 1,                     // cbsz=BF8(e5m2), blgp=BF8
                        0, 0x7F7F7F7F,            // scale A = 1.0
                        0, 0x7F7F7F7F);           // scale B = 1.0
            __builtin_amdgcn_s_setprio(0);
        }
        // --- tile jt complete: fused masked-relu reduce, reset acc ---
        // C/D layout (m89-verified; shape-determined for f8f6f4): col=lane&15,
        // row=(lane>>4)*4+reg.
        const int gi0 = bi * 128;
        const int gj0 = jt * 128 + wn * 32;
        if (jt == bi) {
#pragma unroll
            for (int m = 0; m < 8; ++m)
#pragma unroll
                for (int n = 0; n < 2; ++n) {
#pragma unroll
                    for (int r2 = 0; r2 < 4; ++r2) {
                        const int gi = gi0 + m * 16 + hk * 4 + r2;
                        const int gj = gj0 + n * 16 + lr;
                        local += (gi < gj) ? fmaxf(acc[m][n][r2] - MARGIN, 0.0f) : 0.0f;
                    }
                    acc[m][n] = (f32x4){0.f, 0.f, 0.f, 0.f};
                }
        } else {   // jt > bi: all pairs strictly upper-triangular
#pragma unroll
            for (int m = 0; m < 8; ++m)
#pragma unroll
                for (int n = 0; n < 2; ++n) {
#pragma unroll
                    for (int r2 = 0; r2 < 4; ++r2)
                        local += fmaxf(acc[m][n][r2] - MARGIN, 0.0f);
                    acc[m][n] = (f32x4){0.f, 0.f, 0.f, 0.f};
                }
        }
    }

    // --- block reduction -> one partial per block, no atomics ---
#pragma unroll
    for (int off = 32; off >= 1; off >>= 1) local += __shfl_down(local, off);
    __syncthreads();                          // all loop-LDS traffic done
    if (l == 0) red[w] = local;
    __syncthreads();
    if (t == 0) part[orig] = red[0] + red[1] + red[2] + red[3];
}

// --- Kernel 3: reduce NBLOCKS=442 partials, finalize ---
__global__ __launch_bounds__(256) void fin_kernel(const float* __restrict__ part,
                                                  float* __restrict__ out) {
    __shared__ float red[4];
    const int t = threadIdx.x;
    float v = part[t] + (t < NBLOCKS - 256 ? part[t + 256] : 0.0f);
#pragma unroll
    for (int off = 32; off >= 1; off >>= 1) v += __shfl_down(v, off);
    if ((t & 63) == 0) red[t >> 6] = v;
    __syncthreads();
    if (t == 0) out[0] = (red[0] + red[1] + red[2] + red[3]) / 33550336.0f;
}

extern "C" void kernel_launch(void* const* d_in, const int* in_sizes, int n_in,
                              void* d_out, int out_size, void* d_ws, size_t ws_size,
                              hipStream_t stream) {
    const float* x = (const float*)d_in[0];
    float* out = (float*)d_out;
    unsigned char* e = (unsigned char*)d_ws;                        // 2 MB fp8
    float* part = (float*)((char*)d_ws + (size_t)NROWS * DCOLS);    // 442 floats

    norm_kernel<<<NROWS / 8, 256, 0, stream>>>(x, e);
    tile_kernel<<<NBLOCKS, 256, 0, stream>>>(e, part);
    fin_kernel<<<1, 256, 0, stream>>>(part, out);
}

// Round 29
// 26.472 us; speedup vs baseline: 1.0917x; 1.0646x over previous
//
#include <hip/hip_runtime.h>
#include <hip/hip_fp16.h>

typedef __attribute__((ext_vector_type(4))) float f32x4;
typedef __attribute__((ext_vector_type(8))) int i32x8;

#define NROWS 8192
#define DCOLS 256
#define MARGIN 0.5f
#define NT 64          // 8192/128 tiles per dim
#define NBLOCKS 442    // sum over rows bi of ceil((64-bi)/5), runs of <=5

// --- Kernel 1: L2-normalize rows fp32 -> fp8 e5m2 (= truncated fp16), row-major.
__global__ __launch_bounds__(256) void norm_kernel(const float* __restrict__ x,
                                                   unsigned char* __restrict__ e) {
    const int t = threadIdx.x;
    const int l = t & 63;
    const int c = l & 31;
    const int row = blockIdx.x * 8 + (t >> 6) * 2 + (l >> 5);

    const float4 v0 = *reinterpret_cast<const float4*>(&x[row * DCOLS + c * 8]);
    const float4 v1 = *reinterpret_cast<const float4*>(&x[row * DCOLS + c * 8 + 4]);
    float ss = v0.x * v0.x + v0.y * v0.y + v0.z * v0.z + v0.w * v0.w
             + v1.x * v1.x + v1.y * v1.y + v1.z * v1.z + v1.w * v1.w;
#pragma unroll
    for (int off = 16; off >= 1; off >>= 1) ss += __shfl_xor(ss, off, 32);
    const float inv = 1.0f / fmaxf(sqrtf(ss), 1e-12f);

    const float f[8] = {v0.x, v0.y, v0.z, v0.w, v1.x, v1.y, v1.z, v1.w};
    unsigned int lo = 0, hi = 0;
#pragma unroll
    for (int i = 0; i < 4; ++i) {
        const unsigned short hb = __half_as_ushort(__float2half(f[i] * inv));
        lo |= (unsigned int)(hb >> 8) << (8 * i);           // e5m2 = fp16 top byte
    }
#pragma unroll
    for (int i = 0; i < 4; ++i) {
        const unsigned short hb = __half_as_ushort(__float2half(f[4 + i] * inv));
        hi |= (unsigned int)(hb >> 8) << (8 * i);
    }
    uint2 o; o.x = lo; o.y = hi;
    *reinterpret_cast<uint2*>(e + (size_t)row * DCOLS + c * 8) = o;
}

// --- Kernel 2 (SESSION CHAMPION, 27.8us): MX-fp8 K=128 MFMA + A-in-registers
// + barrier-free wave-private B pipeline + single-generation grid (runs of
// <=5 -> 442 blocks <= 512 co-residency slots, no serial tail). Block =
// (bi, run of <=5 j-tiles), 256 thr = 4 free waves. Tile 128x128; wave owns
// cols wn*32: acc[8][2] of mfma_scale_f32_16x16x128 (bf8/bf8, scale=1.0,
// verified in-context R18). A panel hoisted to af[2][8] regs via 16KB LDS
// bounce (2 rounds); B wave-private 4KB ring-3, own-vmcnt counted gating
// (vmcnt(4)), no in-loop barriers. LDS 64KB -> 2 blocks/CU.
__global__ __launch_bounds__(256, 2) void tile_kernel(const unsigned char* __restrict__ e,
                                                      float* __restrict__ part) {
    // bijective XCD remap for 442 = 8*55 + 2 (m204 q/r formula, ERRATA #11)
    const int orig = blockIdx.x;
    const int xcd = orig & 7, idx = orig >> 3;
    int bb = (xcd < 2 ? xcd * 56 : 2 * 56 + (xcd - 2) * 55) + idx;
    int bi = 0, r;
    while (bb >= (r = ((NT - bi) + 4) / 5)) { bb -= r; ++bi; }
    const int j0 = bi + bb * 5;
    const int nj = min(5, NT - j0);
    const int NS = nj * 2;                    // K128-steps (<=10)

    __shared__ char lds[65536];               // [0,16K): A bounce ; [16K,64K): Bw
    char* As = lds;                           // 16KB: [hk][row128][32B]
    char* Bw = lds + 16384;                   // 4 waves x 3 slots x 4KB
    float* red = (float*)lds;                 // reuse dead A region at the end

    const int t = threadIdx.x;
    const int l = t & 63;
    const int w = t >> 6;       // wave id = N-slice: cols wn*32
    const int wn = w;
    const int lr = l & 15;
    const int hk = l >> 4;
    const unsigned char* eA = e + (size_t)bi * 128 * DCOLS;
    const unsigned char* eB = e + (size_t)j0 * 128 * DCOLS + wn * 32 * DCOLS;
    char* myB = Bw + w * 12288;

    // stage one B K128-panel (stream s: tile j0+(s>>1), kblock s&1) into a slot.
    auto stageB = [&](int stream, int slot) {
#pragma unroll
        for (int i = 0; i < 4; ++i) {
            const int u = i * 64 + l;
            const int shk = (u >> 6) & 3, srow = (u >> 1) & 31, sc = u & 1;
            __builtin_amdgcn_global_load_lds(
                (const __attribute__((address_space(1))) void*)(eB
                    + (size_t)(stream >> 1) * 128 * DCOLS
                    + srow * DCOLS + (stream & 1) * 128 + shk * 32 + sc * 16),
                (__attribute__((address_space(3))) void*)(myB + slot * 4096 + u * 16),
                16, 0, 0);
        }
    };

    // --- prologue ---
    // A round 0 (kblock 0): 4 loads/thread.
#pragma unroll
    for (int i = 0; i < 4; ++i) {
        const int u = i * 256 + t;
        const int shk = (u >> 8) & 3, srow = (u >> 1) & 127, sc = u & 1;
        __builtin_amdgcn_global_load_lds(
            (const __attribute__((address_space(1))) void*)(eA + srow * DCOLS + shk * 32 + sc * 16),
            (__attribute__((address_space(3))) void*)(As + u * 16), 16, 0, 0);
    }
    stageB(0, 0);
    stageB(1, 1);
    asm volatile("s_waitcnt vmcnt(8)" ::: "memory");   // A0 landed; 8 B in flight
    __builtin_amdgcn_s_barrier();
    __builtin_amdgcn_sched_barrier(0);

    i32x8 af[2][8];
#pragma unroll
    for (int m = 0; m < 8; ++m)
        af[0][m] = *reinterpret_cast<const i32x8*>(As + hk * 4096 + (m * 16 + lr) * 32);
    __builtin_amdgcn_s_barrier();             // all waves done reading A0
    __builtin_amdgcn_sched_barrier(0);
    // A round 1 (kblock 1) into the same 16KB
#pragma unroll
    for (int i = 0; i < 4; ++i) {
        const int u = i * 256 + t;
        const int shk = (u >> 8) & 3, srow = (u >> 1) & 127, sc = u & 1;
        __builtin_amdgcn_global_load_lds(
            (const __attribute__((address_space(1))) void*)(eA + srow * DCOLS + 128 + shk * 32 + sc * 16),
            (__attribute__((address_space(3))) void*)(As + u * 16), 16, 0, 0);
    }
    asm volatile("s_waitcnt vmcnt(0)" ::: "memory");   // drain (prologue-only)
    __builtin_amdgcn_s_barrier();
    __builtin_amdgcn_sched_barrier(0);
#pragma unroll
    for (int m = 0; m < 8; ++m)
        af[1][m] = *reinterpret_cast<const i32x8*>(As + hk * 4096 + (m * 16 + lr) * 32);
    // As now dead (red[] reuses it after the loop). B streams 0,1 landed.

    f32x4 acc[8][2];
#pragma unroll
    for (int m = 0; m < 8; ++m)
#pragma unroll
        for (int n = 0; n < 2; ++n)
            acc[m][n] = (f32x4){0.f, 0.f, 0.f, 0.f};

    float local = 0.0f;
    for (int jx = 0; jx < nj; ++jx) {
        const int jt = j0 + jx;
#pragma unroll
        for (int kb = 0; kb < 2; ++kb) {
            const int s = jx * 2 + kb;
            // own oldest B stage has landed (counted; trivially true for s<2)
            asm volatile("s_waitcnt vmcnt(4)" ::: "memory");
            // stage stream s+2 into slot (s+2)%3 (wrap: identical bytes, benign)
            {
                int s2 = s + 2; if (s2 >= NS) s2 -= NS;
                int slot = s + 2; while (slot >= 3) slot -= 3;
                stageB(s2, slot);
            }
            int slotc = s; while (slotc >= 3) slotc -= 3;
            i32x8 bf[2];
#pragma unroll
            for (int n = 0; n < 2; ++n)
                bf[n] = *reinterpret_cast<const i32x8*>(
                    myB + slotc * 4096 + hk * 1024 + (n * 16 + lr) * 32);
            __builtin_amdgcn_s_setprio(1);
#pragma unroll
            for (int m = 0; m < 8; ++m)
#pragma unroll
                for (int n = 0; n < 2; ++n)
                    acc[m][n] = __builtin_amdgcn_mfma_scale_f32_16x16x128_f8f6f4(
                        af[kb][m], bf[n], acc[m][n],
                        1, 1,                     // cbsz=BF8(e5m2), blgp=BF8
                        0, 0x7F7F7F7F,            // scale A = 1.0
                        0, 0x7F7F7F7F);           // scale B = 1.0
            __builtin_amdgcn_s_setprio(0);
        }
        // --- tile jt complete: fused masked-relu reduce, reset acc ---
        // C/D layout (m89-verified; shape-determined for f8f6f4): col=lane&15,
        // row=(lane>>4)*4+reg.
        const int gi0 = bi * 128;
        const int gj0 = jt * 128 + wn * 32;
        if (jt == bi) {
#pragma unroll
            for (int m = 0; m < 8; ++m)
#pragma unroll
                for (int n = 0; n < 2; ++n) {
#pragma unroll
                    for (int r2 = 0; r2 < 4; ++r2) {
                        const int gi = gi0 + m * 16 + hk * 4 + r2;
                        const int gj = gj0 + n * 16 + lr;
                        local += (gi < gj) ? fmaxf(acc[m][n][r2] - MARGIN, 0.0f) : 0.0f;
                    }
                    acc[m][n] = (f32x4){0.f, 0.f, 0.f, 0.f};
                }
        } else {   // jt > bi: all pairs strictly upper-triangular
#pragma unroll
            for (int m = 0; m < 8; ++m)
#pragma unroll
                for (int n = 0; n < 2; ++n) {
#pragma unroll
                    for (int r2 = 0; r2 < 4; ++r2)
                        local += fmaxf(acc[m][n][r2] - MARGIN, 0.0f);
                    acc[m][n] = (f32x4){0.f, 0.f, 0.f, 0.f};
                }
        }
    }

    // --- block reduction -> one partial per block, no atomics ---
#pragma unroll
    for (int off = 32; off >= 1; off >>= 1) local += __shfl_down(local, off);
    __syncthreads();                          // all loop-LDS traffic done
    if (l == 0) red[w] = local;
    __syncthreads();
    if (t == 0) part[orig] = red[0] + red[1] + red[2] + red[3];
}

// --- Kernel 3: reduce NBLOCKS=442 partials, finalize ---
__global__ __launch_bounds__(256) void fin_kernel(const float* __restrict__ part,
                                                  float* __restrict__ out) {
    __shared__ float red[4];
    const int t = threadIdx.x;
    float v = part[t] + (t < NBLOCKS - 256 ? part[t + 256] : 0.0f);
#pragma unroll
    for (int off = 32; off >= 1; off >>= 1) v += __shfl_down(v, off);
    if ((t & 63) == 0) red[t >> 6] = v;
    __syncthreads();
    if (t == 0) out[0] = (red[0] + red[1] + red[2] + red[3]) / 33550336.0f;
}

extern "C" void kernel_launch(void* const* d_in, const int* in_sizes, int n_in,
                              void* d_out, int out_size, void* d_ws, size_t ws_size,
                              hipStream_t stream) {
    const float* x = (const float*)d_in[0];
    float* out = (float*)d_out;
    unsigned char* e = (unsigned char*)d_ws;                        // 2 MB fp8
    float* part = (float*)((char*)d_ws + (size_t)NROWS * DCOLS);    // 442 floats

    norm_kernel<<<NROWS / 8, 256, 0, stream>>>(x, e);
    tile_kernel<<<NBLOCKS, 256, 0, stream>>>(e, part);
    fin_kernel<<<1, 256, 0, stream>>>(part, out);
}